// Round 8
// baseline (5621.375 us; speedup 1.0000x reference)
//
#include <hip/hip_runtime.h>
#include <stdint.h>

// FPS: B=64, N=32768, C=3, S=1024.
// Round-7 structure: 4 blocks per batch (256 blocks = all 256 CUs), each
// block owns a contiguous 8192-point slice. All three coord planes live in
// LDS (96 KB: float2 xy + float z) -> zero global traffic in the hot loop
// and no regalloc fight (rounds 4-6 showed the allocator refuses >64 VGPRs
// and spills instead). Per-step global argmax = intra-block reduce +
// cross-block combine through device-scope atomics in d_ws:
//   publish: slot[b][part][s%4] = (s<<48) | (val_bits<<16) | (0xFFFF-idx)
//   poll:    lanes 0-3 of wave 0 wait for tag==s, u64-max combines
//            (val_bits monotonic for nonneg floats; ~idx gives min-index ties)
// d_ws tags are cleared by hipMemsetAsync each launch, so graph replays
// never see stale tags (writer can then never lap a lagging reader: passing
// the poll of step s-1 proves all peers finished reading step s-2).
// Co-residency: 96KB LDS forces 1 block/CU; 256 blocks on 256 CUs.
// blockIdx = part*B + b puts a batch's 4 parts on the same XCD (heuristic).
//
// Exactness (bit-exact trajectory vs XLA-CPU reference, validated round 3):
//   d = fma(dz,dz, fma(dx,dx, dy*dy)), fminf running min,
//   first-occurrence argmax (strict >, ascending index; min index on ties).
//   Slices are disjoint; combine preserves min-global-index tie-break.

#define FPS_N   32768
#define FPS_S   1024
#define NPARTS  4
#define PPB     (FPS_N / NPARTS)   // 8192 points per block
#define FPS_NT  512
#define PPT     (PPB / FPS_NT)     // 16 points per thread
#define RING    4

typedef unsigned long long u64;
typedef unsigned int u32;

__device__ __forceinline__ u64 shfl_xor_u64(u64 v, int lanemask) {
    int lo = __shfl_xor((int)(u32)(v & 0xFFFFFFFFull), lanemask);
    int hi = __shfl_xor((int)(u32)(v >> 32), lanemask);
    return ((u64)(u32)hi << 32) | (u32)lo;
}

__global__ __launch_bounds__(FPS_NT) void FPSModel_80753975099708_kernel(
    const float* __restrict__ x,   // [B, N, 3]
    float* __restrict__ out_pts,   // [B, S, 3]
    float* __restrict__ out_idx,   // [B, S] (indices stored as float values)
    u64* __restrict__ slots,       // [B][NPARTS][RING], zeroed per launch
    int B)
{
#pragma clang fp contract(off)
    const int part = blockIdx.x / B;          // parts of batch b: b, B+b, 2B+b, 3B+b
    const int b    = blockIdx.x % B;
    const int t    = threadIdx.x;
    const int base = part * PPB;

    const float* __restrict__ xb = x + (size_t)b * FPS_N * 3;
    float* __restrict__ op = out_pts + (size_t)b * FPS_S * 3;
    float* __restrict__ oi = out_idx + (size_t)b * FPS_S;

    __shared__ float2 xy[PPB];                 // 65536 B
    __shared__ float  zs[PPB];                 // 32768 B
    __shared__ float2 red[2][FPS_NT / 64];     // per-wave (value, idx-bits)
    __shared__ int    bc[2];                   // winner broadcast

    float mind[PPT];

    // Prologue: stage this block's slice into LDS.
#pragma unroll
    for (int j = 0; j < PPT; ++j) {
        const int il = j * FPS_NT + t;
        const float* __restrict__ p = xb + (size_t)(base + il) * 3;
        xy[il] = make_float2(p[0], p[1]);
        zs[il] = p[2];
        mind[j] = __int_as_float(0x7f800000);  // +inf
    }

    int cur = 0;
    if (part == 0 && t == 0) {
        oi[0] = 0.0f;
        op[0] = xb[0];
        op[1] = xb[1];
        op[2] = xb[2];
    }
    __syncthreads();

    for (int s = 1; s < FPS_S; ++s) {
        // Broadcast read of current farthest point (12 B, L2-hot).
        const float px = xb[(size_t)cur * 3 + 0];
        const float py = xb[(size_t)cur * 3 + 1];
        const float pz = xb[(size_t)cur * 3 + 2];

        float bestv = __int_as_float(0xff800000); // -inf
        int   bestj = 0;

#pragma unroll
        for (int j = 0; j < PPT; ++j) {
            const int il = j * FPS_NT + t;
            const float2 cxy = xy[il];
            const float dx = cxy.x - px;
            const float dy = cxy.y - py;
            const float dz = zs[il] - pz;
            // XLA-CPU contracted form: fma(dz,dz, fma(dx,dx, dy*dy))
            const float dyy = dy * dy;
            const float u   = __builtin_fmaf(dx, dx, dyy);
            const float d   = __builtin_fmaf(dz, dz, u);
            const float m = fminf(mind[j], d);
            mind[j] = m;
            if (m > bestv) { bestv = m; bestj = j; }  // ascending j => first occ.
        }
        int besti = bestj * FPS_NT + t;               // local slice index

        // Wave butterfly (64 lanes), tie-break to smaller index.
#pragma unroll
        for (int off = 32; off; off >>= 1) {
            const float ov = __shfl_xor(bestv, off);
            const int   ob = __shfl_xor(besti, off);
            if (ov > bestv || (ov == bestv && ob < besti)) { bestv = ov; besti = ob; }
        }
        if ((t & 63) == 0) {
            red[s & 1][t >> 6] = make_float2(bestv, __int_as_float(besti));
        }
        __syncthreads();

        if (t < 64) {
            // Block-level scan of the 8 wave slots (wave 0 only).
            float gv = __int_as_float(0xff800000);
            int   gi = 0x7fffffff;
#pragma unroll
            for (int w = 0; w < FPS_NT / 64; ++w) {
                const float2 e = red[s & 1][w];
                const int ei = __float_as_int(e.y);
                if (e.x > gv || (e.x == gv && ei < gi)) { gv = e.x; gi = ei; }
            }
            const u32 gidx = (u32)(base + gi);        // 15-bit global index
            const u64 key = ((u64)__float_as_uint(gv) << 16) | (u64)(0xFFFFu - gidx);

            if (t == 0) {
                __hip_atomic_store(
                    &slots[(size_t)(b * NPARTS + part) * RING + (s & (RING - 1))],
                    ((u64)(u32)s << 48) | key,
                    __ATOMIC_RELEASE, __HIP_MEMORY_SCOPE_AGENT);
            }

            u64 cand = 0;
            if (t < NPARTS) {
                if (t == part) {
                    cand = key;
                } else {
                    const u64* sl =
                        &slots[(size_t)(b * NPARTS + t) * RING + (s & (RING - 1))];
                    u64 v;
                    do {
                        v = __hip_atomic_load(sl, __ATOMIC_ACQUIRE,
                                              __HIP_MEMORY_SCOPE_AGENT);
                    } while ((u32)(v >> 48) != (u32)s);
                    cand = v & 0x0000FFFFFFFFFFFFull;
                }
            }
            // Combine the 4 candidates (lanes 0-3); max key = max val, min idx.
            u64 o = shfl_xor_u64(cand, 1); if (o > cand) cand = o;
            o     = shfl_xor_u64(cand, 2); if (o > cand) cand = o;
            if (t == 0) bc[s & 1] = (int)(0xFFFFu - (u32)(cand & 0xFFFFu));
        }
        __syncthreads();
        cur = bc[s & 1];

        if (part == 0 && t == 0) {
            oi[s] = (float)cur;
            const float* __restrict__ p = xb + (size_t)cur * 3;
            op[(size_t)s * 3 + 0] = p[0];
            op[(size_t)s * 3 + 1] = p[1];
            op[(size_t)s * 3 + 2] = p[2];
        }
    }
}

extern "C" void kernel_launch(void* const* d_in, const int* in_sizes, int n_in,
                              void* d_out, int out_size, void* d_ws, size_t ws_size,
                              hipStream_t stream) {
    const float* x = (const float*)d_in[0];
    const int B = in_sizes[0] / (FPS_N * 3);

    float* out_pts = (float*)d_out;
    float* out_idx = out_pts + (size_t)B * FPS_S * 3;
    u64* slots = (u64*)d_ws;

    // Clear sync tags every launch (graph-captured; stream-ordered).
    hipMemsetAsync(d_ws, 0, (size_t)B * NPARTS * RING * sizeof(u64), stream);

    hipLaunchKernelGGL(FPSModel_80753975099708_kernel,
                       dim3(B * NPARTS), dim3(FPS_NT), 0, stream,
                       x, out_pts, out_idx, slots, B);
}

// Round 9
// 3919.406 us; speedup vs baseline: 1.4342x; 1.4342x over previous
//
#include <hip/hip_runtime.h>

// FPS: B=64, N=32768, C=3, S=1024. One block per batch (cross-CU per-step
// sync measured at ~4-5us/step in rounds 7/8 -> dead end; single block it is).
//
// Round-9: round 5's limiter was 64 scalar dword loads/thread/step for x,y
// (stride-12 layout). A one-time repack kernel writes xy into d_ws as
// float4 = (x[i],y[i],x[i+1024],y[i+1024]) so the hot loop issues 16
// coalesced global_load_dwordx4 per thread per step from an L2-resident
// 256 KB/block buffer. z plane lives in LDS (131 KB); mind[] in VGPRs.
//
// Exactness (bit-exact trajectory vs XLA-CPU reference, validated round 3/5):
//   d = fma(dz,dz, fma(dx,dx, dy*dy)), fminf running min,
//   first-occurrence argmax (strict >, ascending global index in-thread;
//   min-index tie-break in wave butterfly and block scan). The repack only
//   moves bytes; all compared values are bit-identical to round 5's.

#define FPS_N   32768
#define FPS_S   1024
#define FPS_NT  1024
#define FPS_P   32                 // points per thread
#define NPAIR   (FPS_P / 2)        // 16 float4 loads per thread per step
#define PAIRS_B (FPS_N / 2)        // 16384 float4 per batch

__global__ __launch_bounds__(256) void fps_repack(
    const float* __restrict__ x, float4* __restrict__ xy4, int B)
{
    const int g = blockIdx.x * 256 + threadIdx.x;
    if (g >= B * PAIRS_B) return;
    const int b  = g / PAIRS_B;
    const int p  = g - b * PAIRS_B;
    const int j2 = p >> 10;
    const int t  = p & 1023;
    const int i0 = j2 * 2048 + t;           // pair: (i0, i0+1024)
    const float* __restrict__ xb = x + (size_t)b * FPS_N * 3;
    float4 v;
    v.x = xb[(size_t)i0 * 3 + 0];
    v.y = xb[(size_t)i0 * 3 + 1];
    v.z = xb[(size_t)(i0 + 1024) * 3 + 0];
    v.w = xb[(size_t)(i0 + 1024) * 3 + 1];
    xy4[(size_t)b * PAIRS_B + p] = v;
}

__global__ __launch_bounds__(FPS_NT, 4) void FPSModel_80753975099708_kernel(
    const float* __restrict__ x,        // [B, N, 3] (z + current point reads)
    const float4* __restrict__ xy4,     // [B, PAIRS_B] packed x,y
    float* __restrict__ out_pts,        // [B, S, 3]
    float* __restrict__ out_idx)        // [B, S] (indices as float values)
{
#pragma clang fp contract(off)
    const int b = blockIdx.x;
    const int t = threadIdx.x;
    const float* __restrict__ xb = x + (size_t)b * FPS_N * 3;
    const float4* __restrict__ xy4b = xy4 + (size_t)b * PAIRS_B;
    float* __restrict__ op = out_pts + (size_t)b * FPS_S * 3;
    float* __restrict__ oi = out_idx + (size_t)b * FPS_S;

    __shared__ float zs[FPS_N];                // z plane: 131072 B
    __shared__ float2 red[2][FPS_NT / 64];     // per-wave (value, idx-bits)

    float mind[FPS_P];

    // Prologue: z -> LDS (one-time strided loads), mind -> +inf.
#pragma unroll
    for (int k = 0; k < FPS_P; ++k) {
        const int i = k * FPS_NT + t;
        zs[i] = xb[(size_t)i * 3 + 2];
        mind[k] = __int_as_float(0x7f800000);  // +inf
    }

    int cur = 0;
    if (t == 0) {
        oi[0] = 0.0f;
        op[0] = xb[0];
        op[1] = xb[1];
        op[2] = xb[2];
    }
    __syncthreads();                           // zs visible to all waves

    for (int s = 1; s < FPS_S; ++s) {
        // Broadcast read of current farthest point (12 B, uniform -> scalar).
        const float px = xb[(size_t)cur * 3 + 0];
        const float py = xb[(size_t)cur * 3 + 1];
        const float pz = xb[(size_t)cur * 3 + 2];

        float bestv = __int_as_float(0xff800000); // -inf
        int   besti = 0x7fffffff;

#pragma unroll
        for (int j2 = 0; j2 < NPAIR; ++j2) {
            const float4 v = xy4b[j2 * FPS_NT + t];   // dwordx4, coalesced
            const int ia = j2 * 2048 + t;             // point A index
            const float za = zs[ia];
            const float zb = zs[ia + 1024];
            // point A (global idx ia, mind slot 2*j2)
            {
                const float dx = v.x - px;
                const float dy = v.y - py;
                const float dz = za - pz;
                const float d  = __builtin_fmaf(dz, dz,
                                  __builtin_fmaf(dx, dx, dy * dy));
                const float m = fminf(mind[2 * j2], d);
                mind[2 * j2] = m;
                if (m > bestv) { bestv = m; besti = ia; }
            }
            // point B (global idx ia+1024, mind slot 2*j2+1)
            {
                const float dx = v.z - px;
                const float dy = v.w - py;
                const float dz = zb - pz;
                const float d  = __builtin_fmaf(dz, dz,
                                  __builtin_fmaf(dx, dx, dy * dy));
                const float m = fminf(mind[2 * j2 + 1], d);
                mind[2 * j2 + 1] = m;
                if (m > bestv) { bestv = m; besti = ia + 1024; }
            }
        }

        // Wave butterfly (64 lanes), tie-break to smaller index.
#pragma unroll
        for (int off = 32; off; off >>= 1) {
            const float ov = __shfl_xor(bestv, off);
            const int   ob = __shfl_xor(besti, off);
            if (ov > bestv || (ov == bestv && ob < besti)) { bestv = ov; besti = ob; }
        }

        if ((t & 63) == 0) {
            red[s & 1][t >> 6] = make_float2(bestv, __int_as_float(besti));
        }
        __syncthreads();

        // All threads scan the 16 wave slots identically (broadcast LDS
        // reads); double-buffered red[] makes next iteration's writes safe.
        float gv = __int_as_float(0xff800000);
        int   gi = 0x7fffffff;
#pragma unroll
        for (int w = 0; w < FPS_NT / 64; ++w) {
            const float2 e = red[s & 1][w];
            const int ei = __float_as_int(e.y);
            if (e.x > gv || (e.x == gv && ei < gi)) { gv = e.x; gi = ei; }
        }
        cur = gi;

        if (t == 0) {
            oi[s] = (float)cur;
            const float* __restrict__ p = xb + (size_t)cur * 3;
            op[(size_t)s * 3 + 0] = p[0];
            op[(size_t)s * 3 + 1] = p[1];
            op[(size_t)s * 3 + 2] = p[2];
        }
    }
}

extern "C" void kernel_launch(void* const* d_in, const int* in_sizes, int n_in,
                              void* d_out, int out_size, void* d_ws, size_t ws_size,
                              hipStream_t stream) {
    const float* x = (const float*)d_in[0];
    const int B = in_sizes[0] / (FPS_N * 3);

    float* out_pts = (float*)d_out;
    float* out_idx = out_pts + (size_t)B * FPS_S * 3;
    float4* xy4 = (float4*)d_ws;               // needs B*16384*16 = 16.8 MB

    const int total = B * PAIRS_B;
    hipLaunchKernelGGL(fps_repack, dim3((total + 255) / 256), dim3(256),
                       0, stream, x, xy4, B);

    hipLaunchKernelGGL(FPSModel_80753975099708_kernel,
                       dim3(B), dim3(FPS_NT), 0, stream,
                       x, xy4, out_pts, out_idx);
}

// Round 10
// 3819.275 us; speedup vs baseline: 1.4718x; 1.0262x over previous
//
#include <hip/hip_runtime.h>

// FPS: B=64, N=32768, C=3, S=1024. One block per batch (cross-CU per-step
// sync measured ~4.5us/step in rounds 7/8 -> dead end).
//
// Round-10: rounds 3/5/9 show constant VALU-busy (~0.81us/step) at ~85%
// issue occupancy on the 64 active CUs -> instruction-issue-bound. This
// round halves issue count:
//   * v_pk_{add,mul,fma}_f32 (VOP3P) process 2 points/instr; each half is
//     an independent IEEE RN op -> bit-exact same d = fma(dz,dz,fma(dx,dx,dy*dy)).
//   * phase 1 = min-updates only (no serial argmax chain, pure ILP);
//     in-thread argmax = register tournament tree, prefer-left on tie
//     (= first occurrence), depth 5.
//   * cross-lane/wave argmax via u64 keys (val_bits<<32 | ~idx): single
//     u64 max = max value, tie -> min index. Exact.
//   * readfirstlane(cur) -> scalar loads of the current point.
//   * amdgpu_waves_per_eu(4,4): LDS pins 1 block/CU = 4 waves/SIMD, so let
//     the allocator use up to 128 VGPRs instead of spilling at 64.
//
// Layouts: xy4[b][j2*1024+t] = (x_a, x_b, y_a, y_b), a = j2*2048+t, b = a+1024
//          zs2 (LDS) [j2*1024+t] = (z_a, z_b)  -> one ds_read_b64/pair.
//
// Exactness (bit-exact trajectory vs XLA-CPU reference, validated round 3):
//   d = fma(dz,dz, fma(dx,dx, dy*dy)); dx = x + (-px) == x - px exactly;
//   fminf running min; first-occurrence argmax at every reduction level.

typedef float f32x2 __attribute__((ext_vector_type(2)));
typedef unsigned long long u64;
typedef unsigned int u32;

#define FPS_N   32768
#define FPS_S   1024
#define FPS_NT  1024
#define NPAIR   16                 // float4 pairs per thread
#define PAIRS_B (FPS_N / 2)        // 16384 pairs per batch

__global__ __launch_bounds__(256) void fps_repack(
    const float* __restrict__ x, float4* __restrict__ xy4, int B)
{
    const int g = blockIdx.x * 256 + threadIdx.x;
    if (g >= B * PAIRS_B) return;
    const int b  = g / PAIRS_B;
    const int p  = g - b * PAIRS_B;
    const int j2 = p >> 10;
    const int t  = p & 1023;
    const int ia = j2 * 2048 + t;           // pair: (ia, ia+1024)
    const float* __restrict__ xb = x + (size_t)b * FPS_N * 3;
    float4 v;
    v.x = xb[(size_t)ia * 3 + 0];           // x_a
    v.y = xb[(size_t)(ia + 1024) * 3 + 0];  // x_b
    v.z = xb[(size_t)ia * 3 + 1];           // y_a
    v.w = xb[(size_t)(ia + 1024) * 3 + 1];  // y_b
    xy4[(size_t)b * PAIRS_B + p] = v;
}

__global__ __launch_bounds__(FPS_NT)
__attribute__((amdgpu_waves_per_eu(4, 4)))
void FPSModel_80753975099708_kernel(
    const float* __restrict__ x,        // [B, N, 3]
    const f32x2* __restrict__ xy2,      // packed pairs, 2 per point-pair
    float* __restrict__ out_pts,        // [B, S, 3]
    float* __restrict__ out_idx)        // [B, S] (indices as float values)
{
#pragma clang fp contract(off)
    const int b = blockIdx.x;
    const int t = threadIdx.x;
    const float* __restrict__ xb = x + (size_t)b * FPS_N * 3;
    const f32x2* __restrict__ xyb = xy2 + (size_t)b * PAIRS_B * 2;
    float* __restrict__ op = out_pts + (size_t)b * FPS_S * 3;
    float* __restrict__ oi = out_idx + (size_t)b * FPS_S;

    __shared__ float2 zs2[PAIRS_B];            // 131072 B
    __shared__ u64 red[2][FPS_NT / 64];        // per-wave keys

    float mind[2 * NPAIR];

    // Prologue: z pairs -> LDS; mind -> +inf. One-time strided loads.
#pragma unroll
    for (int j2 = 0; j2 < NPAIR; ++j2) {
        const int ia = j2 * 2048 + t;
        zs2[j2 * FPS_NT + t] =
            make_float2(xb[(size_t)ia * 3 + 2], xb[(size_t)(ia + 1024) * 3 + 2]);
        mind[2 * j2]     = __int_as_float(0x7f800000);
        mind[2 * j2 + 1] = __int_as_float(0x7f800000);
    }

    int cur = 0;
    if (t == 0) {
        oi[0] = 0.0f;
        op[0] = xb[0];
        op[1] = xb[1];
        op[2] = xb[2];
    }
    __syncthreads();

    for (int s = 1; s < FPS_S; ++s) {
        // Current point: uniform -> scalar loads.
        const int curU = __builtin_amdgcn_readfirstlane(cur);
        const float px = xb[(size_t)curU * 3 + 0];
        const float py = xb[(size_t)curU * 3 + 1];
        const float pz = xb[(size_t)curU * 3 + 2];
        f32x2 NX, NY, NZ;
        NX[0] = -px; NX[1] = -px;     // a + (-p) == a - p exactly (RN)
        NY[0] = -py; NY[1] = -py;
        NZ[0] = -pz; NZ[1] = -pz;

        float v0[NPAIR];
        int   k0[NPAIR];

        // Phase 1: packed min-updates, no cross-iteration dependence.
#pragma unroll
        for (int j2 = 0; j2 < NPAIR; ++j2) {
            const f32x2 X = xyb[2 * (j2 * FPS_NT + t)];       // (x_a, x_b)
            const f32x2 Y = xyb[2 * (j2 * FPS_NT + t) + 1];   // (y_a, y_b)
            const f32x2 Z = *(const f32x2*)&zs2[j2 * FPS_NT + t];
            f32x2 DX, DY, DZ, T, T2, D;
            asm("v_pk_add_f32 %0, %1, %2" : "=v"(DX) : "v"(X), "v"(NX));
            asm("v_pk_add_f32 %0, %1, %2" : "=v"(DY) : "v"(Y), "v"(NY));
            asm("v_pk_add_f32 %0, %1, %2" : "=v"(DZ) : "v"(Z), "v"(NZ));
            asm("v_pk_mul_f32 %0, %1, %1" : "=v"(T)  : "v"(DY));
            asm("v_pk_fma_f32 %0, %1, %1, %2" : "=v"(T2) : "v"(DX), "v"(T));
            asm("v_pk_fma_f32 %0, %1, %1, %2" : "=v"(D)  : "v"(DZ), "v"(T2));
            const float ma = fminf(mind[2 * j2],     D[0]);
            const float mb = fminf(mind[2 * j2 + 1], D[1]);
            mind[2 * j2]     = ma;
            mind[2 * j2 + 1] = mb;
            // fused tournament level 0 (strict > : tie keeps lower rank)
            const bool g0 = mb > ma;
            v0[j2] = g0 ? mb : ma;
            k0[j2] = g0 ? (2 * j2 + 1) : (2 * j2);
        }

        // Tournament tree over 16 survivors (prefer-left on tie).
#pragma unroll
        for (int st = 1; st < NPAIR; st <<= 1) {
#pragma unroll
            for (int j = 0; j < NPAIR; j += 2 * st) {
                const bool g2 = v0[j + st] > v0[j];
                v0[j] = g2 ? v0[j + st] : v0[j];
                k0[j] = g2 ? k0[j + st] : k0[j];
            }
        }
        // rank r maps to global index r*1024 + t (ascending in r).
        const u32 besti = (u32)(k0[0] * FPS_NT + t);
        u64 key = ((u64)__float_as_uint(v0[0]) << 32) |
                  (u64)(0xFFFFFFFFu - besti);

        // Wave butterfly: u64 max == max value, tie -> min index.
#pragma unroll
        for (int off = 32; off; off >>= 1) {
            const u64 ok = __shfl_xor((unsigned long long)key, off);
            if (ok > key) key = ok;
        }

        if ((t & 63) == 0) red[s & 1][t >> 6] = key;
        __syncthreads();

        // All threads scan the 16 wave keys (broadcast LDS reads, tree).
        u64 r0[FPS_NT / 64];
#pragma unroll
        for (int w = 0; w < FPS_NT / 64; ++w) r0[w] = red[s & 1][w];
#pragma unroll
        for (int st = 1; st < FPS_NT / 64; st <<= 1) {
#pragma unroll
            for (int w = 0; w < FPS_NT / 64; w += 2 * st) {
                if (r0[w + st] > r0[w]) r0[w] = r0[w + st];
            }
        }
        cur = (int)(0xFFFFFFFFu - (u32)(r0[0] & 0xFFFFFFFFull));

        if (t == 0) {
            oi[s] = (float)cur;
            const float* __restrict__ p = xb + (size_t)cur * 3;
            op[(size_t)s * 3 + 0] = p[0];
            op[(size_t)s * 3 + 1] = p[1];
            op[(size_t)s * 3 + 2] = p[2];
        }
    }
}

extern "C" void kernel_launch(void* const* d_in, const int* in_sizes, int n_in,
                              void* d_out, int out_size, void* d_ws, size_t ws_size,
                              hipStream_t stream) {
    const float* x = (const float*)d_in[0];
    const int B = in_sizes[0] / (FPS_N * 3);

    float* out_pts = (float*)d_out;
    float* out_idx = out_pts + (size_t)B * FPS_S * 3;
    float4* xy4 = (float4*)d_ws;               // B*16384*16 = 16.8 MB

    const int total = B * PAIRS_B;
    hipLaunchKernelGGL(fps_repack, dim3((total + 255) / 256), dim3(256),
                       0, stream, x, xy4, B);

    hipLaunchKernelGGL(FPSModel_80753975099708_kernel,
                       dim3(B), dim3(FPS_NT), 0, stream,
                       x, (const f32x2*)xy4, out_pts, out_idx);
}